// Round 3
// baseline (453.600 us; speedup 1.0000x reference)
//
#include <hip/hip_runtime.h>

#define IN_DIM   2048
#define OUT_DIM  4096
#define MEM_LEN  32768
#define BETA     5000.0f

typedef float f4v __attribute__((ext_vector_type(4)));

// workspace layout (float offsets), ~5.27 MB total
#define WS_PS    0                         // [256][2048] stats partial sums
#define WS_PQ    (WS_PS + 256*2048)        // [256][2048] stats partial sum-squares
#define WS_PG    (WS_PQ + 256*2048)        // [64][4096]  gemv partials
#define WS_NEW   (WS_PG + 64*4096)         // [2048] normalized query
#define WS_ENC   (WS_NEW + 2048)           // [4096] tanh(enc)
#define WS_MINB  (WS_ENC + 4096)           // [64] bucket minima (float bits as uint)

// ---------------------------------------------------------------- init
__global__ void k_init(float* __restrict__ ws) {
    if (threadIdx.x < 64)
        ((unsigned int*)ws)[WS_MINB + threadIdx.x] = 0x7F800000u;  // +inf
}

// ---------------- fused: column partial stats of mem_data + copy to out
// grid (2,256), block 256. Thread owns input float4-group g = bx*256+t
// (512 groups per row), 128-row chunk per blockIdx.y.
// Loads: aligned dwordx4. Stores: out row base is ==1 (mod 4 floats), so
// thread g stores out-group (g-1) = {prev.w, v.x, v.y, v.z} at float index
// 4g-1 (16B-aligned in output space); one shfl_up per store; lane 0 of a
// wave fetches prev.w with a scalar load (L1/L2 hit). Head cols 0..2 and
// tail col L-1 are scalar stores by the edge threads.
__global__ void k_stats_copy(const float* __restrict__ md,
                             float* __restrict__ out_md,
                             float* __restrict__ ws) {
    const int t    = threadIdx.x;
    const int g    = blockIdx.x * 256 + t;    // 0..511
    const int lane = t & 63;
    const int r0   = blockIdx.y * 128;
    const f4v* in4 = (const f4v*)md;
    f4v s = {0.f, 0.f, 0.f, 0.f};
    f4v q = {0.f, 0.f, 0.f, 0.f};
#pragma unroll 4
    for (int i = 0; i < 128; ++i) {
        const size_t r = (size_t)(r0 + i);
        f4v v = __builtin_nontemporal_load(in4 + r * 512 + g);
        s += v; q += v * v;
        float pw = __shfl_up(v.w, 1, 64);
        if (lane == 0 && g > 0)
            pw = __builtin_nontemporal_load(md + r * IN_DIM + 4 * g - 1);
        float* orow = out_md + r * IN_DIM;
        if (g > 0) {
            f4v o; o.x = pw; o.y = v.x; o.z = v.y; o.w = v.z;
            __builtin_nontemporal_store(o, (f4v*)(orow + 4 * g - 1));
        } else {
            orow[0] = v.x; orow[1] = v.y; orow[2] = v.z;
        }
        if (g == 511) orow[IN_DIM - 1] = v.w;
    }
    ((f4v*)(ws + WS_PS))[blockIdx.y * 512 + g] = s;
    ((f4v*)(ws + WS_PQ))[blockIdx.y * 512 + g] = q;
}

// ---------------------------------------------------------------- new = (x-mean)/std
__global__ void k_new(const float* __restrict__ x, float* __restrict__ ws) {
    int c = blockIdx.x * 256 + threadIdx.x;
    float s = 0.0f, q = 0.0f;
    for (int y = 0; y < 256; ++y) {
        s += ws[WS_PS + y * IN_DIM + c];
        q += ws[WS_PQ + y * IN_DIM + c];
    }
    float mean = s * (1.0f / (float)MEM_LEN);
    float var  = (q - s * mean) * (1.0f / (float)(MEM_LEN - 1));  // ddof=1
    float sd   = sqrtf(fmaxf(var, 0.0f));
    ws[WS_NEW + c] = (sd == 0.0f) ? 0.0f : (x[c] - mean) / sd;
}

// ---------------------------------------------------------------- GEMV partials
__global__ void k_gemv(const float* __restrict__ W, float* __restrict__ ws) {
    const int j4 = blockIdx.x * 256 + threadIdx.x;    // 0..1023
    const int i0 = blockIdx.y * 32;
    const f4v* W4 = (const f4v*)W;
    f4v a = {0.f, 0.f, 0.f, 0.f};
#pragma unroll 8
    for (int k = 0; k < 32; ++k) {
        float nv = ws[WS_NEW + i0 + k];
        f4v w = __builtin_nontemporal_load(W4 + (size_t)(i0 + k) * 1024 + j4);
        a += nv * w;
    }
    ((f4v*)(ws + WS_PG))[(size_t)blockIdx.y * 1024 + j4] = a;
}

// ------------------------------------------------ reduce gemv + bias + tanh
__global__ void k_enc(const float* __restrict__ b_enc, float* __restrict__ ws) {
    int j = blockIdx.x * 256 + threadIdx.x;
    float s = b_enc[j];
    for (int y = 0; y < 64; ++y) s += ws[WS_PG + y * OUT_DIM + j];
    ws[WS_ENC + j] = tanhf(s);
}

// ------------------- fused: per-row L1 distance + copy memory to out
// Wave per row (block 256 = 4 rows, grid 8192). Same shifted-store trick:
// thread handling input group g stores out-group g-1 as aligned dwordx4.
__global__ void k_dist_copy(const float* __restrict__ mem,
                            float* __restrict__ out_mem,
                            float* __restrict__ ws) {
    const int lane = threadIdx.x & 63;
    const int wid  = threadIdx.x >> 6;
    const size_t r = (size_t)blockIdx.x * 4 + wid;
    const f4v* in4 = (const f4v*)mem + r * 1024;
    const f4v* e4  = (const f4v*)(ws + WS_ENC);
    const float* irow = mem + r * OUT_DIM;
    float* orow = out_mem + r * OUT_DIM;
    float acc = 0.0f;
#pragma unroll 4
    for (int k = 0; k < 16; ++k) {
        const int g = k * 64 + lane;   // 0..1023
        f4v v = __builtin_nontemporal_load(in4 + g);
        f4v e = e4[g];
        acc += fabsf(v.x - e.x) + fabsf(v.y - e.y) +
               fabsf(v.z - e.z) + fabsf(v.w - e.w);
        float pw = __shfl_up(v.w, 1, 64);
        if (lane == 0 && g > 0)
            pw = __builtin_nontemporal_load(irow + 4 * g - 1);  // L1 hit (lane63 prev iter)
        if (g > 0) {
            f4v o; o.x = pw; o.y = v.x; o.z = v.y; o.w = v.z;
            __builtin_nontemporal_store(o, (f4v*)(orow + 4 * g - 1));
        } else {
            orow[0] = v.x; orow[1] = v.y; orow[2] = v.z;
        }
        if (g == 1023) orow[OUT_DIM - 1] = v.w;
    }
    for (int off = 32; off >= 1; off >>= 1)
        acc += __shfl_down(acc, off, 64);
    __shared__ float wmin[4];
    if (lane == 0) wmin[wid] = acc;
    __syncthreads();
    if (threadIdx.x == 0) {
        float b = fminf(fminf(wmin[0], wmin[1]), fminf(wmin[2], wmin[3]));
        atomicMin((unsigned int*)ws + WS_MINB + (blockIdx.x & 63),
                  __float_as_uint(b));   // b >= 0 so uint-order == float-order
    }
}

// ---------------------------------------------------------------- finalize
__global__ void k_final(const float* __restrict__ x, const int* __restrict__ count,
                        const float* __restrict__ ws, float* __restrict__ d_out) {
    __shared__ float sl;
    int t = threadIdx.x;
    if (t < 64) {
        float v = __uint_as_float(((const unsigned int*)ws)[WS_MINB + t]);
        for (int off = 32; off >= 1; off >>= 1)
            v = fminf(v, __shfl_down(v, off, 64));
        if (t == 0) { d_out[0] = v; sl = v; }
    }
    __syncthreads();
    float loss = sl;
    if (loss <= BETA) {
        int pos = count[0] % MEM_LEN;
        float* outM  = d_out + 1;
        float* outMD = d_out + 1 + (size_t)MEM_LEN * OUT_DIM;
        for (int j = t; j < OUT_DIM; j += 256)
            outM[(size_t)pos * OUT_DIM + j] = ws[WS_ENC + j];
        for (int i = t; i < IN_DIM; i += 256)
            outMD[(size_t)pos * IN_DIM + i] = x[i];
    }
}

extern "C" void kernel_launch(void* const* d_in, const int* in_sizes, int n_in,
                              void* d_out, int out_size, void* d_ws, size_t ws_size,
                              hipStream_t stream) {
    const float* x        = (const float*)d_in[0];
    const float* memory   = (const float*)d_in[1];
    const float* mem_data = (const float*)d_in[2];
    const float* W_enc    = (const float*)d_in[3];
    const float* b_enc    = (const float*)d_in[4];
    const int*   count    = (const int*)d_in[5];
    float* out = (float*)d_out;
    float* ws  = (float*)d_ws;

    float* out_mem = out + 1;                                   // [32768][4096]
    float* out_md  = out + 1 + (size_t)MEM_LEN * OUT_DIM;       // [32768][2048]

    k_init<<<1, 64, 0, stream>>>(ws);
    k_stats_copy<<<dim3(2, 256), 256, 0, stream>>>(mem_data, out_md, ws);
    k_new<<<8, 256, 0, stream>>>(x, ws);
    k_gemv<<<dim3(4, 64), 256, 0, stream>>>(W_enc, ws);
    k_enc<<<16, 256, 0, stream>>>(b_enc, ws);
    k_dist_copy<<<8192, 256, 0, stream>>>(memory, out_mem, ws);
    k_final<<<1, 256, 0, stream>>>(x, count, ws, out);
}

// Round 4
// 347.376 us; speedup vs baseline: 1.3058x; 1.3058x over previous
//
#include <hip/hip_runtime.h>

#define IN_DIM   2048
#define OUT_DIM  4096
#define MEM_LEN  32768
#define BETA     5000.0f

typedef float f4v  __attribute__((ext_vector_type(4)));
typedef f4v   uf4  __attribute__((aligned(4)));   // 4B-aligned float4 (HW allows dword-aligned dwordx4)

// workspace layout (float offsets), ~5.03 MB total
#define WS_PS    0                         // [256][2048] stats partial sums
#define WS_PQ    (WS_PS + 256*2048)        // [256][2048] stats partial sum-squares
#define WS_PG    (WS_PQ + 256*2048)        // [64][4096]  gemv partials
#define WS_NEW   (WS_PG + 64*4096)         // [2048] normalized query
#define WS_ENC   (WS_NEW + 2048)           // [4096] tanh(enc)
#define WS_MINB  (WS_ENC + 4096)           // [64] bucket minima (float bits as uint)

// ---------------- fused: column partial stats of mem_data + copy to out
// grid (2,256), block 256. Thread owns shifted window cols [4g-1 .. 4g+2]
// (g = bx*256+t, 512 windows/row), 128-row chunk per blockIdx.y.
// Load: one 4B-aligned dwordx4 (input). Store: 16B-aligned dwordx4 (output
// base is +1 float, so col 4g-1 is 16B-aligned there). Head thread (g==0)
// covers cols 0..2, tail thread (g==511) additionally col 2047.
__global__ void k_stats_copy(const float* __restrict__ md,
                             float* __restrict__ out_md,
                             float* __restrict__ ws) {
    const int g = blockIdx.x * 256 + threadIdx.x;   // 0..511
    const bool head = (g == 0), tail = (g == 511);
    const int cbase = head ? 0 : 4 * g - 1;
    const int r0 = blockIdx.y * 128;
    f4v s = {0.f,0.f,0.f,0.f}, q = {0.f,0.f,0.f,0.f};
    float s4 = 0.f, q4 = 0.f;
#pragma unroll 4
    for (int i = 0; i < 128; ++i) {
        const size_t r = (size_t)(r0 + i);
        const float* irow = md + r * IN_DIM;
        float*       orow = out_md + r * IN_DIM;
        uf4 v = *(const uf4*)(irow + cbase);
        if (head) v.w = 0.0f;               // col 3 belongs to g==1
        s += v; q += v * v;
        if (head) {
            orow[0] = v.x; orow[1] = v.y; orow[2] = v.z;
        } else {
            __builtin_nontemporal_store(v, (uf4*)(orow + cbase));
        }
        if (tail) {
            float m = irow[IN_DIM - 1];
            s4 += m; q4 += m * m;
            orow[IN_DIM - 1] = m;
        }
    }
    float* ps = ws + WS_PS + blockIdx.y * IN_DIM;
    float* pq = ws + WS_PQ + blockIdx.y * IN_DIM;
    if (head) {
        ps[0] = s.x; ps[1] = s.y; ps[2] = s.z;
        pq[0] = q.x; pq[1] = q.y; pq[2] = q.z;
    } else {
        *(uf4*)(ps + cbase) = s;
        *(uf4*)(pq + cbase) = q;
    }
    if (tail) { ps[IN_DIM - 1] = s4; pq[IN_DIM - 1] = q4; }
}

// ------------------------- new = (x-mean)/std  (+ min-bucket init)
__global__ void k_new(const float* __restrict__ x, float* __restrict__ ws) {
    int c = blockIdx.x * 256 + threadIdx.x;
    if (blockIdx.x == 0 && threadIdx.x < 64)
        ((unsigned int*)ws)[WS_MINB + threadIdx.x] = 0x7F800000u;  // +inf
    float s = 0.0f, q = 0.0f;
    for (int y = 0; y < 256; ++y) {
        s += ws[WS_PS + y * IN_DIM + c];
        q += ws[WS_PQ + y * IN_DIM + c];
    }
    float mean = s * (1.0f / (float)MEM_LEN);
    float var  = (q - s * mean) * (1.0f / (float)(MEM_LEN - 1));  // ddof=1
    float sd   = sqrtf(fmaxf(var, 0.0f));
    ws[WS_NEW + c] = (sd == 0.0f) ? 0.0f : (x[c] - mean) / sd;
}

// ---------------------------------------------------------------- GEMV partials
__global__ void k_gemv(const float* __restrict__ W, float* __restrict__ ws) {
    const int j4 = blockIdx.x * 256 + threadIdx.x;    // 0..1023
    const int i0 = blockIdx.y * 32;
    const f4v* W4 = (const f4v*)W;
    f4v a = {0.f, 0.f, 0.f, 0.f};
#pragma unroll 8
    for (int k = 0; k < 32; ++k) {
        float nv = ws[WS_NEW + i0 + k];
        f4v w = __builtin_nontemporal_load(W4 + (size_t)(i0 + k) * 1024 + j4);
        a += nv * w;
    }
    ((f4v*)(ws + WS_PG))[(size_t)blockIdx.y * 1024 + j4] = a;
}

// ------------------------------------------------ reduce gemv + bias + tanh
__global__ void k_enc(const float* __restrict__ b_enc, float* __restrict__ ws) {
    int j = blockIdx.x * 256 + threadIdx.x;
    float s = b_enc[j];
    for (int y = 0; y < 64; ++y) s += ws[WS_PG + y * OUT_DIM + j];
    ws[WS_ENC + j] = tanhf(s);
}

// ------------------- fused: per-row L1 distance + copy memory to out
// Wave per row (block 256 = 4 rows, grid 8192). Shifted-window trick:
// thread g loads cols [4g-1..4g+2] (4B-aligned dwordx4), stores them
// 16B-aligned in output space. Head covers cols 0..2, tail also col 4095.
__global__ void k_dist_copy(const float* __restrict__ mem,
                            float* __restrict__ out_mem,
                            float* __restrict__ ws) {
    const int lane = threadIdx.x & 63;
    const int wid  = threadIdx.x >> 6;
    const size_t r = (size_t)blockIdx.x * 4 + wid;
    const float* irow = mem + r * OUT_DIM;
    float*       orow = out_mem + r * OUT_DIM;
    const float* enc  = ws + WS_ENC;
    float acc = 0.0f;
#pragma unroll 4
    for (int k = 0; k < 16; ++k) {
        const int g = k * 64 + lane;           // 0..1023
        const bool head = (g == 0), tail = (g == 1023);
        const int cbase = head ? 0 : 4 * g - 1;
        uf4 v = *(const uf4*)(irow + cbase);
        uf4 e = *(const uf4*)(enc + cbase);
        float aw = head ? 0.0f : fabsf(v.w - e.w);   // col 3 belongs to g==1
        acc += fabsf(v.x - e.x) + fabsf(v.y - e.y) + fabsf(v.z - e.z) + aw;
        if (head) {
            orow[0] = v.x; orow[1] = v.y; orow[2] = v.z;
        } else {
            __builtin_nontemporal_store(v, (uf4*)(orow + cbase));
        }
        if (tail) {
            float m = irow[OUT_DIM - 1];
            acc += fabsf(m - enc[OUT_DIM - 1]);
            orow[OUT_DIM - 1] = m;
        }
    }
    for (int off = 32; off >= 1; off >>= 1)
        acc += __shfl_down(acc, off, 64);
    __shared__ float wmin[4];
    if (lane == 0) wmin[wid] = acc;
    __syncthreads();
    if (threadIdx.x == 0) {
        float b = fminf(fminf(wmin[0], wmin[1]), fminf(wmin[2], wmin[3]));
        atomicMin((unsigned int*)ws + WS_MINB + (blockIdx.x & 63),
                  __float_as_uint(b));   // b >= 0 so uint-order == float-order
    }
}

// ---------------------------------------------------------------- finalize
__global__ void k_final(const float* __restrict__ x, const int* __restrict__ count,
                        const float* __restrict__ ws, float* __restrict__ d_out) {
    __shared__ float sl;
    int t = threadIdx.x;
    if (t < 64) {
        float v = __uint_as_float(((const unsigned int*)ws)[WS_MINB + t]);
        for (int off = 32; off >= 1; off >>= 1)
            v = fminf(v, __shfl_down(v, off, 64));
        if (t == 0) { d_out[0] = v; sl = v; }
    }
    __syncthreads();
    float loss = sl;
    if (loss <= BETA) {
        int pos = count[0] % MEM_LEN;
        float* outM  = d_out + 1;
        float* outMD = d_out + 1 + (size_t)MEM_LEN * OUT_DIM;
        for (int j = t; j < OUT_DIM; j += 256)
            outM[(size_t)pos * OUT_DIM + j] = ws[WS_ENC + j];
        for (int i = t; i < IN_DIM; i += 256)
            outMD[(size_t)pos * IN_DIM + i] = x[i];
    }
}

extern "C" void kernel_launch(void* const* d_in, const int* in_sizes, int n_in,
                              void* d_out, int out_size, void* d_ws, size_t ws_size,
                              hipStream_t stream) {
    const float* x        = (const float*)d_in[0];
    const float* memory   = (const float*)d_in[1];
    const float* mem_data = (const float*)d_in[2];
    const float* W_enc    = (const float*)d_in[3];
    const float* b_enc    = (const float*)d_in[4];
    const int*   count    = (const int*)d_in[5];
    float* out = (float*)d_out;
    float* ws  = (float*)d_ws;

    float* out_mem = out + 1;                                   // [32768][4096]
    float* out_md  = out + 1 + (size_t)MEM_LEN * OUT_DIM;       // [32768][2048]

    k_stats_copy<<<dim3(2, 256), 256, 0, stream>>>(mem_data, out_md, ws);
    k_new<<<8, 256, 0, stream>>>(x, ws);
    k_gemv<<<dim3(4, 64), 256, 0, stream>>>(W_enc, ws);
    k_enc<<<16, 256, 0, stream>>>(b_enc, ws);
    k_dist_copy<<<8192, 256, 0, stream>>>(memory, out_mem, ws);
    k_final<<<1, 256, 0, stream>>>(x, count, ws, out);
}